// Round 3
// baseline (97.472 us; speedup 1.0000x reference)
//
#include <hip/hip_runtime.h>
#include <math.h>

constexpr int M_TOK = 8;
constexpr int N_OUT = 8192;
constexpr int K_IN  = 8192;
constexpr int KG    = 64;   // K / G, G = 128
constexpr int R_N   = 4;    // output rows per wave

typedef int   i32x4 __attribute__((ext_vector_type(4)));
typedef float f32x4 __attribute__((ext_vector_type(4)));

// ---------------- Kernel 1: per-token symmetric int8 fake-quant ----------------
__global__ __launch_bounds__(1024) void act_quant_kernel(const float* __restrict__ x,
                                                         float* __restrict__ xq) {
    const int row = blockIdx.x;
    const f32x4* xr = reinterpret_cast<const f32x4*>(x + (size_t)row * K_IN);
    f32x4* oq = reinterpret_cast<f32x4*>(xq + (size_t)row * K_IN);
    const int tid = threadIdx.x;

    f32x4 v0 = xr[tid * 2];
    f32x4 v1 = xr[tid * 2 + 1];

    float m = fmaxf(
        fmaxf(fmaxf(fabsf(v0.x), fabsf(v0.y)), fmaxf(fabsf(v0.z), fabsf(v0.w))),
        fmaxf(fmaxf(fabsf(v1.x), fabsf(v1.y)), fmaxf(fabsf(v1.z), fabsf(v1.w))));

    #pragma unroll
    for (int off = 32; off; off >>= 1) m = fmaxf(m, __shfl_xor(m, off));

    __shared__ float smax[16];
    if ((tid & 63) == 0) smax[tid >> 6] = m;
    __syncthreads();
    float mm = smax[0];
    #pragma unroll
    for (int i = 1; i < 16; ++i) mm = fmaxf(mm, smax[i]);

    const float s = fmaxf(mm / 127.0f, 1e-8f);

    auto quant = [&](float v) -> float {
        float q = rintf(v / s);              // numpy round = half-to-even
        q = fminf(fmaxf(q, -127.0f), 127.0f);
        return q * s;
    };

    f32x4 o0, o1;
    o0.x = quant(v0.x); o0.y = quant(v0.y); o0.z = quant(v0.z); o0.w = quant(v0.w);
    o1.x = quant(v1.x); o1.y = quant(v1.y); o1.z = quant(v1.z); o1.w = quant(v1.w);
    oq[tid * 2]     = o0;
    oq[tid * 2 + 1] = o1;
}

// ---------------- Kernel 2: dequant + skinny GEMM, software-pipelined ----------------
// One wave: R_N=4 output rows across full K. Weight loads (HBM, zero reuse) are
// nontemporal and prefetched 1 iteration ahead into named registers; xq loads
// (L1/L2-hot 256 KiB) are plain loads in the current iteration.
__global__ __launch_bounds__(256) void qlin_kernel(const float* __restrict__ xq,
                                                   const int* __restrict__ qw,
                                                   const float* __restrict__ scales,
                                                   const float* __restrict__ bias,
                                                   float* __restrict__ out) {
    const int wave = blockIdx.x * 4 + (threadIdx.x >> 6);
    const int lane = threadIdx.x & 63;
    const int n0 = wave * R_N;
    const int lk = lane * 4;

    float acc[R_N][M_TOK];
    #pragma unroll
    for (int r = 0; r < R_N; ++r)
        #pragma unroll
        for (int m = 0; m < M_TOK; ++m) acc[r][m] = 0.0f;

    const int* wp0 = qw + (size_t)(n0 + 0) * K_IN + lk;
    const int* wp1 = qw + (size_t)(n0 + 1) * K_IN + lk;
    const int* wp2 = qw + (size_t)(n0 + 2) * K_IN + lk;
    const int* wp3 = qw + (size_t)(n0 + 3) * K_IN + lk;
    const float* sp0 = scales + (size_t)(n0 + 0) * KG;
    const float* sp1 = scales + (size_t)(n0 + 1) * KG;
    const float* sp2 = scales + (size_t)(n0 + 2) * KG;
    const float* sp3 = scales + (size_t)(n0 + 3) * KG;

    // prefetch iteration 0
    i32x4 cA0 = __builtin_nontemporal_load(reinterpret_cast<const i32x4*>(wp0));
    i32x4 cA1 = __builtin_nontemporal_load(reinterpret_cast<const i32x4*>(wp1));
    i32x4 cA2 = __builtin_nontemporal_load(reinterpret_cast<const i32x4*>(wp2));
    i32x4 cA3 = __builtin_nontemporal_load(reinterpret_cast<const i32x4*>(wp3));
    int g0 = lk >> 7;
    float sA0 = sp0[g0], sA1 = sp1[g0], sA2 = sp2[g0], sA3 = sp3[g0];

    for (int kb = 0; kb < K_IN; kb += 256) {
        // ---- issue next iteration's weight + scale loads (prefetch) ----
        const int kn = (kb + 256 < K_IN) ? kb + 256 : 0;   // last-iter clamp (harmless re-read)
        i32x4 cB0 = __builtin_nontemporal_load(reinterpret_cast<const i32x4*>(wp0 + kn));
        i32x4 cB1 = __builtin_nontemporal_load(reinterpret_cast<const i32x4*>(wp1 + kn));
        i32x4 cB2 = __builtin_nontemporal_load(reinterpret_cast<const i32x4*>(wp2 + kn));
        i32x4 cB3 = __builtin_nontemporal_load(reinterpret_cast<const i32x4*>(wp3 + kn));
        const int gn = (kn + lk) >> 7;
        float sB0 = sp0[gn], sB1 = sp1[gn], sB2 = sp2[gn], sB3 = sp3[gn];

        // ---- current iteration's xq loads (cache-hot) ----
        const int k = kb + lk;
        f32x4 xv[M_TOK];
        #pragma unroll
        for (int m = 0; m < M_TOK; ++m)
            xv[m] = *reinterpret_cast<const f32x4*>(xq + (size_t)m * K_IN + k);

        // ---- compute with prefetched weights ----
        {
            const float w0 = (float)cA0.x * sA0, w1 = (float)cA0.y * sA0,
                        w2 = (float)cA0.z * sA0, w3 = (float)cA0.w * sA0;
            #pragma unroll
            for (int m = 0; m < M_TOK; ++m) {
                float a = acc[0][m];
                a = fmaf(w0, xv[m].x, a); a = fmaf(w1, xv[m].y, a);
                a = fmaf(w2, xv[m].z, a); a = fmaf(w3, xv[m].w, a);
                acc[0][m] = a;
            }
        }
        {
            const float w0 = (float)cA1.x * sA1, w1 = (float)cA1.y * sA1,
                        w2 = (float)cA1.z * sA1, w3 = (float)cA1.w * sA1;
            #pragma unroll
            for (int m = 0; m < M_TOK; ++m) {
                float a = acc[1][m];
                a = fmaf(w0, xv[m].x, a); a = fmaf(w1, xv[m].y, a);
                a = fmaf(w2, xv[m].z, a); a = fmaf(w3, xv[m].w, a);
                acc[1][m] = a;
            }
        }
        {
            const float w0 = (float)cA2.x * sA2, w1 = (float)cA2.y * sA2,
                        w2 = (float)cA2.z * sA2, w3 = (float)cA2.w * sA2;
            #pragma unroll
            for (int m = 0; m < M_TOK; ++m) {
                float a = acc[2][m];
                a = fmaf(w0, xv[m].x, a); a = fmaf(w1, xv[m].y, a);
                a = fmaf(w2, xv[m].z, a); a = fmaf(w3, xv[m].w, a);
                acc[2][m] = a;
            }
        }
        {
            const float w0 = (float)cA3.x * sA3, w1 = (float)cA3.y * sA3,
                        w2 = (float)cA3.z * sA3, w3 = (float)cA3.w * sA3;
            #pragma unroll
            for (int m = 0; m < M_TOK; ++m) {
                float a = acc[3][m];
                a = fmaf(w0, xv[m].x, a); a = fmaf(w1, xv[m].y, a);
                a = fmaf(w2, xv[m].z, a); a = fmaf(w3, xv[m].w, a);
                acc[3][m] = a;
            }
        }

        // ---- rotate prefetch buffers (SSA rename, no scratch) ----
        cA0 = cB0; cA1 = cB1; cA2 = cB2; cA3 = cB3;
        sA0 = sB0; sA1 = sB1; sA2 = sB2; sA3 = sB3;
    }

    // full butterfly reduce
    #pragma unroll
    for (int r = 0; r < R_N; ++r)
        #pragma unroll
        for (int m = 0; m < M_TOK; ++m) {
            float v = acc[r][m];
            #pragma unroll
            for (int off = 32; off; off >>= 1) v += __shfl_xor(v, off);
            acc[r][m] = v;
        }

    if (lane < R_N * M_TOK) {
        const int rsel = lane >> 3;
        const int msel = lane & 7;
        float myv = 0.0f;
        #pragma unroll
        for (int r = 0; r < R_N; ++r)
            #pragma unroll
            for (int m = 0; m < M_TOK; ++m)
                if (r == rsel && m == msel) myv = acc[r][m];
        out[(size_t)msel * N_OUT + n0 + rsel] = myv + bias[n0 + rsel];
    }
}

extern "C" void kernel_launch(void* const* d_in, const int* in_sizes, int n_in,
                              void* d_out, int out_size, void* d_ws, size_t ws_size,
                              hipStream_t stream) {
    const float* x      = (const float*)d_in[0];
    const int*   qw     = (const int*)d_in[1];
    const float* scales = (const float*)d_in[2];
    const float* bias   = (const float*)d_in[3];
    float* out = (float*)d_out;
    float* xq  = (float*)d_ws;  // M*K floats = 256 KiB scratch

    act_quant_kernel<<<M_TOK, 1024, 0, stream>>>(x, xq);

    const int waves  = N_OUT / R_N;        // 2048
    const int blocks = waves / 4;          // 512 blocks x 256 threads
    qlin_kernel<<<blocks, 256, 0, stream>>>(xq, qw, scales, bias, out);
}

// Round 4
// 69.133 us; speedup vs baseline: 1.4099x; 1.4099x over previous
//
#include <hip/hip_runtime.h>
#include <math.h>

constexpr int M_TOK = 8;
constexpr int N_OUT = 8192;
constexpr int K_IN  = 8192;
constexpr int KG    = 64;   // K / G, G = 128
constexpr int R_N   = 4;    // output rows per wave
constexpr int SPLIT = 2;    // K split factor
constexpr int KHALF = K_IN / SPLIT;  // 4096

typedef int   i32x4 __attribute__((ext_vector_type(4)));
typedef float f32x4 __attribute__((ext_vector_type(4)));

// ---------------- Kernel 1: per-token symmetric int8 fake-quant ----------------
__global__ __launch_bounds__(1024) void act_quant_kernel(const float* __restrict__ x,
                                                         float* __restrict__ xq) {
    const int row = blockIdx.x;
    const f32x4* xr = reinterpret_cast<const f32x4*>(x + (size_t)row * K_IN);
    f32x4* oq = reinterpret_cast<f32x4*>(xq + (size_t)row * K_IN);
    const int tid = threadIdx.x;

    f32x4 v0 = xr[tid * 2];
    f32x4 v1 = xr[tid * 2 + 1];

    float m = fmaxf(
        fmaxf(fmaxf(fabsf(v0.x), fabsf(v0.y)), fmaxf(fabsf(v0.z), fabsf(v0.w))),
        fmaxf(fmaxf(fabsf(v1.x), fabsf(v1.y)), fmaxf(fabsf(v1.z), fabsf(v1.w))));

    #pragma unroll
    for (int off = 32; off; off >>= 1) m = fmaxf(m, __shfl_xor(m, off));

    __shared__ float smax[16];
    if ((tid & 63) == 0) smax[tid >> 6] = m;
    __syncthreads();
    float mm = smax[0];
    #pragma unroll
    for (int i = 1; i < 16; ++i) mm = fmaxf(mm, smax[i]);

    const float s = fmaxf(mm / 127.0f, 1e-8f);

    auto quant = [&](float v) -> float {
        float q = rintf(v / s);              // numpy round = half-to-even
        q = fminf(fmaxf(q, -127.0f), 127.0f);
        return q * s;
    };

    f32x4 o0, o1;
    o0.x = quant(v0.x); o0.y = quant(v0.y); o0.z = quant(v0.z); o0.w = quant(v0.w);
    o1.x = quant(v1.x); o1.y = quant(v1.y); o1.z = quant(v1.z); o1.w = quant(v1.w);
    oq[tid * 2]     = o0;
    oq[tid * 2 + 1] = o1;
}

// ---------------- Kernel 2: dequant + skinny GEMM, split-K ----------------
// wave -> (n-quad, K-half). 1024 blocks x 4 waves = 4096 waves = 4 waves/SIMD.
// Round-1 loop body: plain cached loads, compiler-scheduled (manual prefetch
// and nontemporal both REGRESSED in round 3 — do not reintroduce).
__global__ __launch_bounds__(256) void qlin_kernel(const float* __restrict__ xq,
                                                   const int* __restrict__ qw,
                                                   const float* __restrict__ scales,
                                                   float* __restrict__ partial) {
    const int wave = blockIdx.x * 4 + (threadIdx.x >> 6);
    const int lane = threadIdx.x & 63;
    const int half = wave & (SPLIT - 1);
    const int n0 = (wave / SPLIT) * R_N;
    const int kbase = half * KHALF;
    const int lk = lane * 4;

    float acc[R_N][M_TOK];
    #pragma unroll
    for (int r = 0; r < R_N; ++r)
        #pragma unroll
        for (int m = 0; m < M_TOK; ++m) acc[r][m] = 0.0f;

    for (int kb = kbase; kb < kbase + KHALF; kb += 256) {
        const int k = kb + lk;
        const int g = k >> 7;  // group index; 4 consecutive k share one group

        f32x4 xv[M_TOK];
        #pragma unroll
        for (int m = 0; m < M_TOK; ++m)
            xv[m] = *reinterpret_cast<const f32x4*>(xq + (size_t)m * K_IN + k);

        #pragma unroll
        for (int r = 0; r < R_N; ++r) {
            const i32x4 c =
                *reinterpret_cast<const i32x4*>(qw + (size_t)(n0 + r) * K_IN + k);
            const float sc = scales[(size_t)(n0 + r) * KG + g];
            const float w0 = (float)c.x * sc;
            const float w1 = (float)c.y * sc;
            const float w2 = (float)c.z * sc;
            const float w3 = (float)c.w * sc;
            #pragma unroll
            for (int m = 0; m < M_TOK; ++m) {
                float a = acc[r][m];
                a = fmaf(w0, xv[m].x, a);
                a = fmaf(w1, xv[m].y, a);
                a = fmaf(w2, xv[m].z, a);
                a = fmaf(w3, xv[m].w, a);
                acc[r][m] = a;
            }
        }
    }

    // full butterfly reduce -> every lane holds each (r,m) total
    #pragma unroll
    for (int r = 0; r < R_N; ++r)
        #pragma unroll
        for (int m = 0; m < M_TOK; ++m) {
            float v = acc[r][m];
            #pragma unroll
            for (int off = 32; off; off >>= 1) v += __shfl_xor(v, off);
            acc[r][m] = v;
        }

    // lane (r*8 + m) writes partial[half][m][n0+r]
    if (lane < R_N * M_TOK) {
        const int rsel = lane >> 3;
        const int msel = lane & 7;
        float myv = 0.0f;
        #pragma unroll
        for (int r = 0; r < R_N; ++r)
            #pragma unroll
            for (int m = 0; m < M_TOK; ++m)
                if (r == rsel && m == msel) myv = acc[r][m];
        partial[((size_t)half * M_TOK + msel) * N_OUT + n0 + rsel] = myv;
    }
}

// ---------------- Kernel 3: combine split-K partials + bias ----------------
// out[m][n] = p[0][m][n] + p[1][m][n] + bias[n]; fixed order -> deterministic.
__global__ __launch_bounds__(256) void reduce_kernel(const float* __restrict__ partial,
                                                     const float* __restrict__ bias,
                                                     float* __restrict__ out) {
    const int idx = blockIdx.x * 256 + threadIdx.x;   // f32x4 chunk id, 16384 total
    const int m  = idx >> 11;                          // 2048 chunks per m row
    const int nc = idx & 2047;
    const f32x4* p = reinterpret_cast<const f32x4*>(partial);
    const f32x4 p0 = p[((size_t)0 * M_TOK + m) * 2048 + nc];
    const f32x4 p1 = p[((size_t)1 * M_TOK + m) * 2048 + nc];
    const f32x4 b  = reinterpret_cast<const f32x4*>(bias)[nc];
    f32x4 o;
    o.x = p0.x + p1.x + b.x;
    o.y = p0.y + p1.y + b.y;
    o.z = p0.z + p1.z + b.z;
    o.w = p0.w + p1.w + b.w;
    reinterpret_cast<f32x4*>(out)[(size_t)m * 2048 + nc] = o;
}

extern "C" void kernel_launch(void* const* d_in, const int* in_sizes, int n_in,
                              void* d_out, int out_size, void* d_ws, size_t ws_size,
                              hipStream_t stream) {
    const float* x      = (const float*)d_in[0];
    const int*   qw     = (const int*)d_in[1];
    const float* scales = (const float*)d_in[2];
    const float* bias   = (const float*)d_in[3];
    float* out = (float*)d_out;

    float* partial = (float*)d_ws;                          // SPLIT*M*N floats = 512 KiB
    float* xq      = partial + (size_t)SPLIT * M_TOK * N_OUT;  // M*K floats = 256 KiB

    act_quant_kernel<<<M_TOK, 1024, 0, stream>>>(x, xq);

    const int waves  = (N_OUT / R_N) * SPLIT;   // 4096
    const int blocks = waves / 4;               // 1024 blocks x 256 threads
    qlin_kernel<<<blocks, 256, 0, stream>>>(xq, qw, scales, partial);

    reduce_kernel<<<(M_TOK * N_OUT / 4) / 256, 256, 0, stream>>>(partial, bias, out);
}

// Round 5
// 68.679 us; speedup vs baseline: 1.4192x; 1.0066x over previous
//
#include <hip/hip_runtime.h>
#include <math.h>

constexpr int M_TOK = 8;
constexpr int N_OUT = 8192;
constexpr int K_IN  = 8192;
constexpr int KG    = 64;   // K / G, G = 128
constexpr int R_N   = 4;    // output rows per wave
constexpr int SPLIT = 2;    // K split factor
constexpr int KHALF = K_IN / SPLIT;  // 4096
constexpr int CHUNK = 256;  // k per staged chunk

typedef int   i32x4 __attribute__((ext_vector_type(4)));
typedef float f32x4 __attribute__((ext_vector_type(4)));

// ---------------- Kernel 1: per-token symmetric int8 fake-quant ----------------
__global__ __launch_bounds__(1024) void act_quant_kernel(const float* __restrict__ x,
                                                         float* __restrict__ xq) {
    const int row = blockIdx.x;
    const f32x4* xr = reinterpret_cast<const f32x4*>(x + (size_t)row * K_IN);
    f32x4* oq = reinterpret_cast<f32x4*>(xq + (size_t)row * K_IN);
    const int tid = threadIdx.x;

    f32x4 v0 = xr[tid * 2];
    f32x4 v1 = xr[tid * 2 + 1];

    float m = fmaxf(
        fmaxf(fmaxf(fabsf(v0.x), fabsf(v0.y)), fmaxf(fabsf(v0.z), fabsf(v0.w))),
        fmaxf(fmaxf(fabsf(v1.x), fabsf(v1.y)), fmaxf(fabsf(v1.z), fabsf(v1.w))));

    #pragma unroll
    for (int off = 32; off; off >>= 1) m = fmaxf(m, __shfl_xor(m, off));

    __shared__ float smax[16];
    if ((tid & 63) == 0) smax[tid >> 6] = m;
    __syncthreads();
    float mm = smax[0];
    #pragma unroll
    for (int i = 1; i < 16; ++i) mm = fmaxf(mm, smax[i]);

    const float s = fmaxf(mm / 127.0f, 1e-8f);

    auto quant = [&](float v) -> float {
        float q = rintf(v / s);              // numpy round = half-to-even
        q = fminf(fmaxf(q, -127.0f), 127.0f);
        return q * s;
    };

    f32x4 o0, o1;
    o0.x = quant(v0.x); o0.y = quant(v0.y); o0.z = quant(v0.z); o0.w = quant(v0.w);
    o1.x = quant(v1.x); o1.y = quant(v1.y); o1.z = quant(v1.z); o1.w = quant(v1.w);
    oq[tid * 2]     = o0;
    oq[tid * 2 + 1] = o1;
}

// ---------------- Kernel 2: dequant + skinny GEMM, split-K, LDS-shared xq ----------------
// Block = 16 output rows x K-half; 4 waves share one k-range. xq chunk (8 rows x
// 256 k = 8 KiB) is cooperatively staged into double-buffered LDS, cutting xq
// global traffic 4x (the round-4 bottleneck: 512 MiB of L3-served xq re-reads).
// Weight loads stay plain cached streams (manual prefetch/nontemporal REGRESSED
// in round 3 — do not reintroduce).
__global__ __launch_bounds__(256) void qlin_kernel(const float* __restrict__ xq,
                                                   const int* __restrict__ qw,
                                                   const float* __restrict__ scales,
                                                   float* __restrict__ partial) {
    __shared__ float xs[2][M_TOK][CHUNK];   // 16 KiB

    const int widx = threadIdx.x >> 6;      // wave in block, 0..3
    const int lane = threadIdx.x & 63;
    const int half = blockIdx.x & (SPLIT - 1);
    const int nblk = blockIdx.x >> 1;       // 0..511
    const int n0 = nblk * 16 + widx * R_N;  // this wave's 4 output rows
    const int kbase = half * KHALF;
    const int lk = lane * 4;

    float acc[R_N][M_TOK];
    #pragma unroll
    for (int r = 0; r < R_N; ++r)
        #pragma unroll
        for (int m = 0; m < M_TOK; ++m) acc[r][m] = 0.0f;

    // cooperative stage of one 8-row x 256-k chunk into xs[buf]
    auto stage = [&](int buf, int kb) {
        #pragma unroll
        for (int i = 0; i < 2; ++i) {
            const int idx = threadIdx.x + i * 256;   // 0..511
            const int row = idx >> 6;                // 0..7
            const int c4  = (idx & 63) << 2;         // 0..252
            const f32x4 v = *reinterpret_cast<const f32x4*>(
                xq + (size_t)row * K_IN + kb + c4);
            *reinterpret_cast<f32x4*>(&xs[buf][row][c4]) = v;
        }
    };

    stage(0, kbase);
    __syncthreads();
    int buf = 0;

    constexpr int NT = KHALF / CHUNK;   // 16
    for (int t = 0; t < NT; ++t) {
        const int kb = kbase + t * CHUNK;
        if (t + 1 < NT) stage(buf ^ 1, kb + CHUNK);

        const int k = kb + lk;
        const int g = k >> 7;   // scale group; 4 consecutive k share one group

        f32x4 xv[M_TOK];
        #pragma unroll
        for (int m = 0; m < M_TOK; ++m)
            xv[m] = *reinterpret_cast<const f32x4*>(&xs[buf][m][lk]);

        #pragma unroll
        for (int r = 0; r < R_N; ++r) {
            const i32x4 c =
                *reinterpret_cast<const i32x4*>(qw + (size_t)(n0 + r) * K_IN + k);
            const float sc = scales[(size_t)(n0 + r) * KG + g];
            const float w0 = (float)c.x * sc;
            const float w1 = (float)c.y * sc;
            const float w2 = (float)c.z * sc;
            const float w3 = (float)c.w * sc;
            #pragma unroll
            for (int m = 0; m < M_TOK; ++m) {
                float a = acc[r][m];
                a = fmaf(w0, xv[m].x, a);
                a = fmaf(w1, xv[m].y, a);
                a = fmaf(w2, xv[m].z, a);
                a = fmaf(w3, xv[m].w, a);
                acc[r][m] = a;
            }
        }

        __syncthreads();
        buf ^= 1;
    }

    // full butterfly reduce -> every lane holds each (r,m) total
    #pragma unroll
    for (int r = 0; r < R_N; ++r)
        #pragma unroll
        for (int m = 0; m < M_TOK; ++m) {
            float v = acc[r][m];
            #pragma unroll
            for (int off = 32; off; off >>= 1) v += __shfl_xor(v, off);
            acc[r][m] = v;
        }

    // lane (r*8 + m) writes partial[half][m][n0+r]
    if (lane < R_N * M_TOK) {
        const int rsel = lane >> 3;
        const int msel = lane & 7;
        float myv = 0.0f;
        #pragma unroll
        for (int r = 0; r < R_N; ++r)
            #pragma unroll
            for (int m = 0; m < M_TOK; ++m)
                if (r == rsel && m == msel) myv = acc[r][m];
        partial[((size_t)half * M_TOK + msel) * N_OUT + n0 + rsel] = myv;
    }
}

// ---------------- Kernel 3: combine split-K partials + bias ----------------
__global__ __launch_bounds__(256) void reduce_kernel(const float* __restrict__ partial,
                                                     const float* __restrict__ bias,
                                                     float* __restrict__ out) {
    const int idx = blockIdx.x * 256 + threadIdx.x;   // f32x4 chunk id, 16384 total
    const int m  = idx >> 11;                          // 2048 chunks per m row
    const int nc = idx & 2047;
    const f32x4* p = reinterpret_cast<const f32x4*>(partial);
    const f32x4 p0 = p[((size_t)0 * M_TOK + m) * 2048 + nc];
    const f32x4 p1 = p[((size_t)1 * M_TOK + m) * 2048 + nc];
    const f32x4 b  = reinterpret_cast<const f32x4*>(bias)[nc];
    f32x4 o;
    o.x = p0.x + p1.x + b.x;
    o.y = p0.y + p1.y + b.y;
    o.z = p0.z + p1.z + b.z;
    o.w = p0.w + p1.w + b.w;
    reinterpret_cast<f32x4*>(out)[(size_t)m * 2048 + nc] = o;
}

extern "C" void kernel_launch(void* const* d_in, const int* in_sizes, int n_in,
                              void* d_out, int out_size, void* d_ws, size_t ws_size,
                              hipStream_t stream) {
    const float* x      = (const float*)d_in[0];
    const int*   qw     = (const int*)d_in[1];
    const float* scales = (const float*)d_in[2];
    const float* bias   = (const float*)d_in[3];
    float* out = (float*)d_out;

    float* partial = (float*)d_ws;                             // SPLIT*M*N floats = 512 KiB
    float* xq      = partial + (size_t)SPLIT * M_TOK * N_OUT;  // M*K floats = 256 KiB

    act_quant_kernel<<<M_TOK, 1024, 0, stream>>>(x, xq);

    const int blocks = (N_OUT / 16) * SPLIT;   // 1024 blocks x 256 threads
    qlin_kernel<<<blocks, 256, 0, stream>>>(xq, qw, scales, partial);

    reduce_kernel<<<(M_TOK * N_OUT / 4) / 256, 256, 0, stream>>>(partial, bias, out);
}

// Round 6
// 66.971 us; speedup vs baseline: 1.4555x; 1.0255x over previous
//
#include <hip/hip_runtime.h>
#include <math.h>

constexpr int M_TOK = 8;
constexpr int N_OUT = 8192;
constexpr int K_IN  = 8192;
constexpr int KG    = 64;   // K / G, G = 128
constexpr int R_N   = 4;    // output rows per wave
constexpr int CHUNK = 512;  // k per staged chunk

typedef int   i32x4 __attribute__((ext_vector_type(4)));
typedef float f32x4 __attribute__((ext_vector_type(4)));

// ---------------- Kernel A: per-token scales only (8 floats to ws) ----------------
__global__ __launch_bounds__(1024) void scales_kernel(const float* __restrict__ x,
                                                      float* __restrict__ sout) {
    const int row = blockIdx.x;
    const f32x4* xr = reinterpret_cast<const f32x4*>(x + (size_t)row * K_IN);
    const int tid = threadIdx.x;

    f32x4 v0 = xr[tid * 2];
    f32x4 v1 = xr[tid * 2 + 1];

    float m = fmaxf(
        fmaxf(fmaxf(fabsf(v0.x), fabsf(v0.y)), fmaxf(fabsf(v0.z), fabsf(v0.w))),
        fmaxf(fmaxf(fabsf(v1.x), fabsf(v1.y)), fmaxf(fabsf(v1.z), fabsf(v1.w))));

    #pragma unroll
    for (int off = 32; off; off >>= 1) m = fmaxf(m, __shfl_xor(m, off));

    __shared__ float smax[16];
    if ((tid & 63) == 0) smax[tid >> 6] = m;
    __syncthreads();
    if (tid == 0) {
        float mm = smax[0];
        #pragma unroll
        for (int i = 1; i < 16; ++i) mm = fmaxf(mm, smax[i]);
        sout[row] = fmaxf(mm / 127.0f, 1e-8f);  // numpy: true div, clamp
    }
}

// ---------------- Kernel B: fused fake-quant + dequant-GEMM + bias ----------------
// Block = 16 output rows x full K. Staging reads x (L2-hot) and applies the int8
// fake-quant on the fly (s from ws). Weights: plain cached loads, two 1-KiB
// bursts per row per iteration (2 KiB contiguous). No split-K, direct out write.
// (Manual prefetch / nontemporal REGRESSED in round 3 — do not reintroduce.)
__global__ __launch_bounds__(256) void qlin_kernel(const float* __restrict__ x,
                                                   const int* __restrict__ qw,
                                                   const float* __restrict__ scales,
                                                   const float* __restrict__ bias,
                                                   const float* __restrict__ srow,
                                                   float* __restrict__ out) {
    __shared__ float xs[2][M_TOK][CHUNK];   // 32 KiB

    const int widx = threadIdx.x >> 6;      // wave in block, 0..3
    const int lane = threadIdx.x & 63;
    const int n0 = blockIdx.x * 16 + widx * R_N;
    const int lk = lane * 4;

    float acc[R_N][M_TOK];
    #pragma unroll
    for (int r = 0; r < R_N; ++r)
        #pragma unroll
        for (int m = 0; m < M_TOK; ++m) acc[r][m] = 0.0f;

    // stage one 8-row x 512-k chunk of x, quantizing on the fly.
    // per (wave, i) the source row is wave-uniform: row = (widx + 4i) >> 1.
    auto stage = [&](int buf, int kb) {
        #pragma unroll
        for (int i = 0; i < 4; ++i) {
            const int row = (widx + 4 * i) >> 1;               // wave-uniform
            const int c4  = (((widx & 1) << 6) + lane) << 2;   // 0..508
            const float s = srow[row];                         // L1-hot dword
            f32x4 v = *reinterpret_cast<const f32x4*>(x + (size_t)row * K_IN + kb + c4);
            f32x4 q;
            q.x = fminf(fmaxf(rintf(v.x / s), -127.0f), 127.0f) * s;
            q.y = fminf(fmaxf(rintf(v.y / s), -127.0f), 127.0f) * s;
            q.z = fminf(fmaxf(rintf(v.z / s), -127.0f), 127.0f) * s;
            q.w = fminf(fmaxf(rintf(v.w / s), -127.0f), 127.0f) * s;
            *reinterpret_cast<f32x4*>(&xs[buf][row][c4]) = q;
        }
    };

    stage(0, 0);
    __syncthreads();
    int buf = 0;

    constexpr int NT = K_IN / CHUNK;   // 16
    for (int t = 0; t < NT; ++t) {
        const int kb = t * CHUNK;
        if (t + 1 < NT) stage(buf ^ 1, kb + CHUNK);

        const int k1 = kb + lk;          // first sub-block
        const int k2 = kb + 256 + lk;    // second sub-block
        const int g1 = k1 >> 7;          // 4 consecutive k share one group
        const int g2 = k2 >> 7;

        f32x4 xa[M_TOK], xb[M_TOK];
        #pragma unroll
        for (int m = 0; m < M_TOK; ++m) {
            xa[m] = *reinterpret_cast<const f32x4*>(&xs[buf][m][lk]);
            xb[m] = *reinterpret_cast<const f32x4*>(&xs[buf][m][256 + lk]);
        }

        #pragma unroll
        for (int r = 0; r < R_N; ++r) {
            const int* wrow = qw + (size_t)(n0 + r) * K_IN;
            const i32x4 c1 = *reinterpret_cast<const i32x4*>(wrow + k1);
            const i32x4 c2 = *reinterpret_cast<const i32x4*>(wrow + k2);
            const float sc1 = scales[(size_t)(n0 + r) * KG + g1];
            const float sc2 = scales[(size_t)(n0 + r) * KG + g2];
            const float w0 = (float)c1.x * sc1, w1 = (float)c1.y * sc1,
                        w2 = (float)c1.z * sc1, w3 = (float)c1.w * sc1;
            const float u0 = (float)c2.x * sc2, u1 = (float)c2.y * sc2,
                        u2 = (float)c2.z * sc2, u3 = (float)c2.w * sc2;
            #pragma unroll
            for (int m = 0; m < M_TOK; ++m) {
                float a = acc[r][m];
                a = fmaf(w0, xa[m].x, a); a = fmaf(w1, xa[m].y, a);
                a = fmaf(w2, xa[m].z, a); a = fmaf(w3, xa[m].w, a);
                a = fmaf(u0, xb[m].x, a); a = fmaf(u1, xb[m].y, a);
                a = fmaf(u2, xb[m].z, a); a = fmaf(u3, xb[m].w, a);
                acc[r][m] = a;
            }
        }

        __syncthreads();
        buf ^= 1;
    }

    // full butterfly reduce -> every lane holds each (r,m) total
    #pragma unroll
    for (int r = 0; r < R_N; ++r)
        #pragma unroll
        for (int m = 0; m < M_TOK; ++m) {
            float v = acc[r][m];
            #pragma unroll
            for (int off = 32; off; off >>= 1) v += __shfl_xor(v, off);
            acc[r][m] = v;
        }

    // lane (r*8 + m) writes out[m][n0+r] + bias
    if (lane < R_N * M_TOK) {
        const int rsel = lane >> 3;
        const int msel = lane & 7;
        float myv = 0.0f;
        #pragma unroll
        for (int r = 0; r < R_N; ++r)
            #pragma unroll
            for (int m = 0; m < M_TOK; ++m)
                if (r == rsel && m == msel) myv = acc[r][m];
        out[(size_t)msel * N_OUT + n0 + rsel] = myv + bias[n0 + rsel];
    }
}

extern "C" void kernel_launch(void* const* d_in, const int* in_sizes, int n_in,
                              void* d_out, int out_size, void* d_ws, size_t ws_size,
                              hipStream_t stream) {
    const float* x      = (const float*)d_in[0];
    const int*   qw     = (const int*)d_in[1];
    const float* scales = (const float*)d_in[2];
    const float* bias   = (const float*)d_in[3];
    float* out  = (float*)d_out;
    float* srow = (float*)d_ws;   // 8 floats

    scales_kernel<<<M_TOK, 1024, 0, stream>>>(x, srow);

    const int blocks = N_OUT / 16;   // 512 blocks x 256 threads
    qlin_kernel<<<blocks, 256, 0, stream>>>(x, qw, scales, bias, srow, out);
}